// Round 8
// baseline (23503.612 us; speedup 1.0000x reference)
//
#include <hip/hip_runtime.h>

// TinyRNNPolicy: h_{t+1} = tanh(W h_t); action_t = tanh(mean(h_{t+1}[:2048]))
//
// R11 = R10 transport (proven) + two CU-side cuts:
//  1) ROW-PER-WAVE DIRECT PUBLISH: wave w computes row w fully (64 lanes x
//     64 cols, shuffle-reduce) and lane0 publishes that dword IMMEDIATELY --
//     no barrier, no wave0 combine, no combine-drain on the critical path.
//     Readers already validate per-dword (data-is-flag), so staggered
//     per-row publication is natively supported. The parts/readout combine
//     runs after barrier (C), off the critical path.
//  2) PACKED BF16 DOT: W (128KB) and h (8KB) both live in LDS as packed
//     bf16 pairs; hot loop = 8 x {2 ds_read_b128 + 4 v_dot2_f32_bf16} per
//     lane (guarded by __has_builtin; unpack-FMA fallback) -- 32 VALU ops
//     vs R10's 128 (R10's unpack doubled VALUBusy to 24%). h is still
//     TRANSPORTED as fp32 (~bit encode) for full precision; packed to
//     bf16 once per step at staging.
// Layouts (conflict-free by construction):
//   wl[w*2048 + j*256 + lane*4 + e] = pack(W[row w][c], W[row w][c+1]),
//     c = j*512 + lane*8 + 2e  (== linear c/2 within row) -> b128 reads,
//     consecutive lanes.
//   hs[j*256 + lane*4 + e] likewise (== linear c/2) -> b128, consecutive.
//   staging: thread t writes hs[2t], hs[2t+1] (stride-2 = free 2-way).
// Transport (R10-proven): 256 blocks x 1024 thr; per-thread 4-dword
// data-is-flag spin (~bits; ~bits==0 only for NaN 0xFFFFFFFF, tanh never
// makes it); 4-buffer rotation, clears post-(A) (at step s, (A) proves all
// blocks completed s-1, so none is mid-spin on B[(s+2)&3]; clear ordered
// before that buffer's rewrite by each wave's pre-publish vmcnt + (C)).

#define N 4096
#define HALF 2048
#define BLOCKS 256
#define TPB 1024
#define RPB 16

// ws layout (dword offsets); ws re-poisoned each launch -> init kernel.
#define WS_FLAGS 0            // 256 flags, stride 16 dwords (final barrier)
#define WS_HA    4096         // h buffer 0 (~bits)
#define WS_HB    8192         // h buffer 1
#define WS_HC    12288        // h buffer 2
#define WS_HD    16384        // h buffer 3
#define WS_ACC   20480        // accum[out_size] (fallback path only)
#define WS_PART  24576        // parts[n_steps*128] (big path)

typedef unsigned u32x4 __attribute__((ext_vector_type(4)));

#if defined(__has_builtin)
#if __has_builtin(__builtin_amdgcn_fdot2_f32_bf16)
#define HAVE_DOT2 1
typedef __bf16 bf16x2 __attribute__((ext_vector_type(2)));
#endif
#endif
#ifndef HAVE_DOT2
#define HAVE_DOT2 0
#endif

__device__ __forceinline__ float agent_ld(const float* p) {
    return __hip_atomic_load(p, __ATOMIC_RELAXED, __HIP_MEMORY_SCOPE_AGENT);
}
__device__ __forceinline__ void agent_st(float* p, float v) {
    __hip_atomic_store(p, v, __ATOMIC_RELAXED, __HIP_MEMORY_SCOPE_AGENT);
}
__device__ __forceinline__ unsigned agent_ldu(const unsigned* p) {
    return __hip_atomic_load(p, __ATOMIC_RELAXED, __HIP_MEMORY_SCOPE_AGENT);
}
__device__ __forceinline__ void agent_stu(unsigned* p, unsigned v) {
    __hip_atomic_store(p, v, __ATOMIC_RELAXED, __HIP_MEMORY_SCOPE_AGENT);
}

__device__ __forceinline__ float tanh_fast(float x) {
    x = fminf(fmaxf(x, -15.0f), 15.0f);   // clamp avoids inf/inf
    float e = __expf(2.0f * x);
    return (e - 1.0f) / (e + 1.0f);       // exact 0 at x==0
}

__device__ __forceinline__ unsigned bf16_rne(float x) {   // fp32 -> bf16 (RNE)
    unsigned u = __float_as_uint(x);
    return (u + 0x7FFFu + ((u >> 16) & 1u)) >> 16;
}
__device__ __forceinline__ float bf_lo(unsigned d) { return __uint_as_float(d << 16); }
__device__ __forceinline__ float bf_hi(unsigned d) { return __uint_as_float(d & 0xFFFF0000u); }

// c += dot(2 bf16 pairs). dot2 is symmetric in its packed operands; only
// the pairing matters, so semantics are pinned even if the builtin's
// operand naming differs.
__device__ __forceinline__ float dot2bf(unsigned wp, unsigned hp, float c) {
#if HAVE_DOT2
    return __builtin_amdgcn_fdot2_f32_bf16(__builtin_bit_cast(bf16x2, wp),
                                           __builtin_bit_cast(bf16x2, hp),
                                           c, false);
#else
    c = fmaf(bf_lo(wp), bf_lo(hp), c);
    c = fmaf(bf_hi(wp), bf_hi(hp), c);
    return c;
#endif
}

__global__ void rnn_init(const float* __restrict__ h0, float* __restrict__ ws, int n_out) {
    int i = blockIdx.x * blockDim.x + threadIdx.x;
    if (i < BLOCKS * 16) agent_stu((unsigned*)ws + WS_FLAGS + i, 0u);
    if (i < n_out) agent_st(ws + WS_ACC + i, 0.0f);
    if (i < N) {
        agent_stu((unsigned*)ws + WS_HA + i, ~__float_as_uint(h0[i]));  // h^0
        agent_stu((unsigned*)ws + WS_HB + i, 0u);   // invalid
        agent_stu((unsigned*)ws + WS_HC + i, 0u);   // invalid
        agent_stu((unsigned*)ws + WS_HD + i, 0u);   // invalid
    }
}

__global__ void __launch_bounds__(TPB, 4)
rnn_persistent(const float* __restrict__ W, const int* __restrict__ pns,
               float* __restrict__ out, float* __restrict__ ws, int big) {
    const int b    = blockIdx.x;
    const int t    = threadIdx.x;
    const int lane = t & 63;
    const int wave = t >> 6;       // 0..15 == row within block

    __shared__ __align__(16) unsigned wl[32768];  // W bf16 pairs (128 KiB)
    __shared__ __align__(16) unsigned hs[2048];   // h bf16 pairs (8 KiB)
    __shared__ float part[16];                    // per-row h (readout only)

    // ---- one-time: W row 'wave' -> LDS packed bf16 (coalesced reads) ----
    {
        const float* Wr = W + (size_t)(b * RPB + wave) * N;
#pragma unroll
        for (int j = 0; j < 8; ++j) {
            const float* c0 = Wr + j * 512 + lane * 8;
            float4 va = *(const float4*)(c0);
            float4 vb = *(const float4*)(c0 + 4);
            u32x4 d;
            d.x = bf16_rne(va.x) | (bf16_rne(va.y) << 16);
            d.y = bf16_rne(va.z) | (bf16_rne(va.w) << 16);
            d.z = bf16_rne(vb.x) | (bf16_rne(vb.y) << 16);
            d.w = bf16_rne(vb.z) | (bf16_rne(vb.w) << 16);
            *(u32x4*)&wl[wave * 2048 + j * 256 + lane * 4] = d;
        }
    }
    __syncthreads();

    const int n_steps = *pns;

    unsigned* flags = (unsigned*)ws + WS_FLAGS;
    float* accum = ws + WS_ACC;
    float* parts = ws + WS_PART;

    // rotation: read p0=B[s&3], write p1=B[(s+1)&3], clear p2=B[(s+2)&3]
    unsigned* p0 = (unsigned*)ws + WS_HA;
    unsigned* p1 = (unsigned*)ws + WS_HB;
    unsigned* p2 = (unsigned*)ws + WS_HC;
    unsigned* p3 = (unsigned*)ws + WS_HD;

    for (int s = 0; s < n_steps; ++s) {
        // ---- fused spin + h ingest: wait until all 4 of my dwords valid ----
        unsigned a0, a1, a2, a3;
        {
            const unsigned* src = p0 + 4 * t;
            unsigned spins = 0;
            for (;;) {
                a0 = agent_ldu(src + 0); a1 = agent_ldu(src + 1);
                a2 = agent_ldu(src + 2); a3 = agent_ldu(src + 3);
                if (min(min(a0, a1), min(a2, a3)) != 0u) break;
                __builtin_amdgcn_s_sleep(1);
                if (++spins > (1u << 22)) break;   // fail loud, don't hang
            }
        }
        // decode fp32, pack to bf16 pairs, stage (stride-2 write = free)
        {
            unsigned d0 = bf16_rne(__uint_as_float(~a0)) |
                          (bf16_rne(__uint_as_float(~a1)) << 16);
            unsigned d1 = bf16_rne(__uint_as_float(~a2)) |
                          (bf16_rne(__uint_as_float(~a3)) << 16);
            *(uint2*)&hs[2 * t] = make_uint2(d0, d1);
        }
        __syncthreads();   // (A): all of h^s observed + staged block-wide

        // clear the buffer last read at s-2 (race-free: (A) proves every
        // block completed step s-1, so none is mid-spin on p2). Ordered
        // before its rewrite (step s+1) by this wave's pre-publish vmcnt
        // below + (C)+(A,s+1) ordering for other waves.
        if (t < RPB) agent_stu(p2 + b * RPB + t, 0u);

        // ---- row 'wave': 8 x {2 b128 + 4 dot2} over packed bf16 ----
        float acc = 0.0f;
        {
            const unsigned* wrow = wl + wave * 2048 + lane * 4;
            const unsigned* hrow = hs + lane * 4;
#pragma unroll
            for (int j = 0; j < 8; ++j) {
                u32x4 wd = *(const u32x4*)(wrow + j * 256);
                u32x4 hd = *(const u32x4*)(hrow + j * 256);
                acc = dot2bf(wd.x, hd.x, acc);
                acc = dot2bf(wd.y, hd.y, acc);
                acc = dot2bf(wd.z, hd.z, acc);
                acc = dot2bf(wd.w, hd.w, acc);
            }
        }
        // 64-lane reduce -> lane0
        acc += __shfl_down(acc, 32);
        acc += __shfl_down(acc, 16);
        acc += __shfl_down(acc, 8);
        acc += __shfl_down(acc, 4);
        acc += __shfl_down(acc, 2);
        acc += __shfl_down(acc, 1);

        // ---- DIRECT per-wave publish: no barrier, no combine on path ----
        float hval = tanh_fast(acc);
        if (lane == 0) part[wave] = hval;
        // wave-level drain: this wave's old stores (wave0's clears ~compute
        // old; last step's readout) -- then the one publish dword.
        asm volatile("s_waitcnt vmcnt(0)" ::: "memory");
        if (lane == 0)
            agent_stu(p1 + b * RPB + wave, ~__float_as_uint(hval));

        __syncthreads();   // (C): part[] complete; publishes all issued

        // ---- readout of step s: fully off the critical path ----
        if (wave == 0) {
            float rv = (lane < RPB) ? part[lane] : 0.0f;
            rv += __shfl_down(rv, 8);
            rv += __shfl_down(rv, 4);
            rv += __shfl_down(rv, 2);
            rv += __shfl_down(rv, 1);
            if (lane == 0 && b < (HALF / RPB)) {  // blocks 0..127 own rows<2048
                if (big) agent_st(parts + (size_t)s * 128 + b, rv);
                else     atomicAdd(accum + s, rv);
            }
            // fallback: adds for s-1 drained (publishers' pre-publish vmcnt
            // at step s covered their s-1 adds; we observed their publishes)
            if (!big && b == 0 && lane == 32 && s > 0)
                out[s-1] = tanh_fast(agent_ld(accum + s - 1) * (1.0f / (float)HALF));
        }

        // rotate: p_i <- B[(s+1+i)&3]
        unsigned* tmp = p0; p0 = p1; p1 = p2; p2 = p3; p3 = tmp;
    }

    // ---- one-time device barrier so 'parts'/accum stores are visible ----
    asm volatile("s_waitcnt vmcnt(0)" ::: "memory");
    __syncthreads();
    if (t == 0) agent_stu(flags + b * 16, 1u);
    if (t < BLOCKS) {
        unsigned spins = 0;
        while (agent_ldu(flags + t * 16) == 0u) {
            __builtin_amdgcn_s_sleep(1);
            if (++spins > (1u << 22)) break;
        }
    }
    __syncthreads();

    if (big) {
        // all outputs in parallel: 128 block-partials per step
        for (int ss = b * 16 + wave; ss < n_steps; ss += BLOCKS * 16) {
            float v2 = agent_ld(parts + (size_t)ss * 128 + lane)
                     + agent_ld(parts + (size_t)ss * 128 + 64 + lane);
            v2 += __shfl_down(v2, 32);
            v2 += __shfl_down(v2, 16);
            v2 += __shfl_down(v2, 8);
            v2 += __shfl_down(v2, 4);
            v2 += __shfl_down(v2, 2);
            v2 += __shfl_down(v2, 1);
            if (lane == 0) out[ss] = tanh_fast(v2 * (1.0f / (float)HALF));
        }
    } else if (b == 0 && t == 0 && n_steps > 0) {
        out[n_steps-1] = tanh_fast(agent_ld(accum + n_steps - 1) * (1.0f / (float)HALF));
    }
}

extern "C" void kernel_launch(void* const* d_in, const int* in_sizes, int n_in,
                              void* d_out, int out_size, void* d_ws, size_t ws_size,
                              hipStream_t stream) {
    const float* W  = (const float*)d_in[0];
    const float* h0 = (const float*)d_in[1];
    const int*  pns = (const int*)d_in[2];
    float* out = (float*)d_out;
    float* ws  = (float*)d_ws;

    size_t need = ((size_t)WS_PART + (size_t)out_size * 128) * 4;
    int big = (ws_size >= need) ? 1 : 0;

    int n_init = out_size > N ? out_size : N;
    rnn_init<<<(n_init + 255) / 256, 256, 0, stream>>>(h0, ws, out_size);
    rnn_persistent<<<BLOCKS, TPB, 0, stream>>>(W, pns, out, ws, big);
}

// Round 9
// 11592.558 us; speedup vs baseline: 2.0275x; 2.0275x over previous
//
#include <hip/hip_runtime.h>

// TinyRNNPolicy: h_{t+1} = tanh(W h_t); action_t = tanh(mean(h_{t+1}[:2048]))
//
// R12 = compose the measured-good halves of R10 and R11, minus their
// measured-bad halves, + bf16 wire format for h:
//  - W in LDS as packed bf16 (R10-proven: kills the uncontrollable L2
//    W-restream; VGPR ~52, conflicts 0).
//  - Row-per-wave dot2 compute (R11-proven: VALUBusy 24->10.5%, 0 conflicts;
//    16 b128 + 32 v_dot2 per lane per step).
//  - Wave0 COALESCED publish (R10-proven; R11's per-wave publish was the
//    23.5ms regression: 16 partial-line LLC writes + max-over-16-waves
//    completion).
//  - NEW: h transported as packed bf16 pairs (~bit encode). Halves the
//    coherent traffic (4MB -> 2MB/step device-wide), poll = ONE 8B atomic
//    load per thread per round, publish = 8 dwords (32B) per block, and
//    staging is a raw copy (the dot2 loop eats packed pairs; zero repack
//    VALU -- R10's unpack mistake avoided). Validity: dword==0 only for
//    ~pack == double-0xFFFF = two bf16 NaNs, which tanh never produces.
//  - Readout moved fully AFTER the publish (was partially before in R10).
// Transport protocol otherwise R10-proven: 256 blocks x 1024 thr; 4-buffer
// rotation (read B[s&3], write B[(s+1)&3], clear B[(s+2)&3] post-(A) --
// at step s, (A) proves all blocks completed s-1, so none is mid-spin on
// B[(s+2)&3]; clear ordered before that buffer's rewrite by the owner's
// next pre-publish vmcnt(0)).

#define N 4096
#define HALF 2048
#define BLOCKS 256
#define TPB 1024
#define RPB 16
#define HWORDS (N / 2)        // 2048 packed dwords per h buffer

// ws layout (dword offsets); ws re-poisoned each launch -> init kernel.
#define WS_FLAGS 0            // 256 flags, stride 16 dwords (final barrier)
#define WS_HA    4096         // h buffer 0 (packed bf16 pairs, ~bits)
#define WS_HB    8192         // h buffer 1
#define WS_HC    12288        // h buffer 2
#define WS_HD    16384        // h buffer 3
#define WS_ACC   20480        // accum[out_size] (fallback path only)
#define WS_PART  24576        // parts[n_steps*128] (big path)

typedef unsigned u32x4 __attribute__((ext_vector_type(4)));

#if defined(__has_builtin)
#if __has_builtin(__builtin_amdgcn_fdot2_f32_bf16)
#define HAVE_DOT2 1
typedef __bf16 bf16x2 __attribute__((ext_vector_type(2)));
#endif
#endif
#ifndef HAVE_DOT2
#define HAVE_DOT2 0
#endif

__device__ __forceinline__ float agent_ld(const float* p) {
    return __hip_atomic_load(p, __ATOMIC_RELAXED, __HIP_MEMORY_SCOPE_AGENT);
}
__device__ __forceinline__ void agent_st(float* p, float v) {
    __hip_atomic_store(p, v, __ATOMIC_RELAXED, __HIP_MEMORY_SCOPE_AGENT);
}
__device__ __forceinline__ unsigned agent_ldu(const unsigned* p) {
    return __hip_atomic_load(p, __ATOMIC_RELAXED, __HIP_MEMORY_SCOPE_AGENT);
}
__device__ __forceinline__ void agent_stu(unsigned* p, unsigned v) {
    __hip_atomic_store(p, v, __ATOMIC_RELAXED, __HIP_MEMORY_SCOPE_AGENT);
}
__device__ __forceinline__ unsigned long long agent_ldu64(const unsigned long long* p) {
    return __hip_atomic_load(p, __ATOMIC_RELAXED, __HIP_MEMORY_SCOPE_AGENT);
}

__device__ __forceinline__ float tanh_fast(float x) {
    x = fminf(fmaxf(x, -15.0f), 15.0f);   // clamp avoids inf/inf
    float e = __expf(2.0f * x);
    return (e - 1.0f) / (e + 1.0f);       // exact 0 at x==0
}

__device__ __forceinline__ unsigned bf16_rne(float x) {   // fp32 -> bf16 (RNE)
    unsigned u = __float_as_uint(x);
    return (u + 0x7FFFu + ((u >> 16) & 1u)) >> 16;
}
__device__ __forceinline__ float bf_lo(unsigned d) { return __uint_as_float(d << 16); }
__device__ __forceinline__ float bf_hi(unsigned d) { return __uint_as_float(d & 0xFFFF0000u); }

// c += dot of 2 packed bf16 pairs (pairing-symmetric)
__device__ __forceinline__ float dot2bf(unsigned wp, unsigned hp, float c) {
#if HAVE_DOT2
    return __builtin_amdgcn_fdot2_f32_bf16(__builtin_bit_cast(bf16x2, wp),
                                           __builtin_bit_cast(bf16x2, hp),
                                           c, false);
#else
    c = fmaf(bf_lo(wp), bf_lo(hp), c);
    c = fmaf(bf_hi(wp), bf_hi(hp), c);
    return c;
#endif
}

__global__ void rnn_init(const float* __restrict__ h0, float* __restrict__ ws, int n_out) {
    int i = blockIdx.x * blockDim.x + threadIdx.x;
    if (i < BLOCKS * 16) agent_stu((unsigned*)ws + WS_FLAGS + i, 0u);
    if (i < n_out) agent_st(ws + WS_ACC + i, 0.0f);
    if (i < HWORDS) {
        unsigned d = bf16_rne(h0[2*i]) | (bf16_rne(h0[2*i+1]) << 16);
        agent_stu((unsigned*)ws + WS_HA + i, ~d);   // h^0, packed ~bits
        agent_stu((unsigned*)ws + WS_HB + i, 0u);   // invalid
        agent_stu((unsigned*)ws + WS_HC + i, 0u);   // invalid
        agent_stu((unsigned*)ws + WS_HD + i, 0u);   // invalid
    }
}

__global__ void __launch_bounds__(TPB, 4)
rnn_persistent(const float* __restrict__ W, const int* __restrict__ pns,
               float* __restrict__ out, float* __restrict__ ws, int big) {
    const int b    = blockIdx.x;
    const int t    = threadIdx.x;
    const int lane = t & 63;
    const int wave = t >> 6;       // 0..15 == row within block

    __shared__ __align__(16) unsigned wl[32768];  // W bf16 pairs (128 KiB)
    __shared__ __align__(16) unsigned hs[HWORDS]; // h bf16 pairs (8 KiB)
    __shared__ float part[16];                    // per-row h (tail+readout)

    // ---- one-time: W row 'wave' -> LDS packed bf16 (coalesced reads) ----
    // wl[wave*2048 + j*256 + lane*4 + e] = pack(W[row][c], W[row][c+1]),
    // c = j*512 + lane*8 + 2e  -> consecutive-lane b128, conflict-free.
    {
        const float* Wr = W + (size_t)(b * RPB + wave) * N;
#pragma unroll
        for (int j = 0; j < 8; ++j) {
            const float* c0 = Wr + j * 512 + lane * 8;
            float4 va = *(const float4*)(c0);
            float4 vb = *(const float4*)(c0 + 4);
            u32x4 d;
            d.x = bf16_rne(va.x) | (bf16_rne(va.y) << 16);
            d.y = bf16_rne(va.z) | (bf16_rne(va.w) << 16);
            d.z = bf16_rne(vb.x) | (bf16_rne(vb.y) << 16);
            d.w = bf16_rne(vb.z) | (bf16_rne(vb.w) << 16);
            *(u32x4*)&wl[wave * 2048 + j * 256 + lane * 4] = d;
        }
    }
    __syncthreads();

    const int n_steps = *pns;

    unsigned* flags = (unsigned*)ws + WS_FLAGS;
    float* accum = ws + WS_ACC;
    float* parts = ws + WS_PART;

    // rotation: read p0=B[s&3], write p1=B[(s+1)&3], clear p2=B[(s+2)&3]
    unsigned* p0 = (unsigned*)ws + WS_HA;
    unsigned* p1 = (unsigned*)ws + WS_HB;
    unsigned* p2 = (unsigned*)ws + WS_HC;
    unsigned* p3 = (unsigned*)ws + WS_HD;

    for (int s = 0; s < n_steps; ++s) {
        // ---- fused spin + ingest: ONE 8B load, both dwords valid ----
        unsigned lo, hi;
        {
            const unsigned long long* src = (const unsigned long long*)(p0 + 2 * t);
            unsigned spins = 0;
            for (;;) {
                unsigned long long q = agent_ldu64(src);
                lo = (unsigned)q; hi = (unsigned)(q >> 32);
                if (min(lo, hi) != 0u) break;
                __builtin_amdgcn_s_sleep(1);
                if (++spins > (1u << 22)) break;   // fail loud, don't hang
            }
        }
        // stage: raw packed copy (no repack -- dot2 eats pairs directly)
        *(uint2*)&hs[2 * t] = make_uint2(~lo, ~hi);
        __syncthreads();   // (A): all of h^s observed + staged block-wide

        // clear buffer last read at s-2 (race-free post-(A); ordered before
        // its rewrite at s+1 by wave0's pre-publish vmcnt(0) next steps)
        if (t < 8) agent_stu(p2 + 8 * b + t, 0u);

        // ---- row 'wave': 8 x {2 b128 + 4 dot2} over packed bf16 ----
        float acc = 0.0f;
        {
            const unsigned* wrow = wl + wave * 2048 + lane * 4;
            const unsigned* hrow = hs + lane * 4;
#pragma unroll
            for (int j = 0; j < 8; ++j) {
                u32x4 wd = *(const u32x4*)(wrow + j * 256);
                u32x4 hd = *(const u32x4*)(hrow + j * 256);
                acc = dot2bf(wd.x, hd.x, acc);
                acc = dot2bf(wd.y, hd.y, acc);
                acc = dot2bf(wd.z, hd.z, acc);
                acc = dot2bf(wd.w, hd.w, acc);
            }
        }
        // 64-lane reduce -> lane0
        acc += __shfl_down(acc, 32);
        acc += __shfl_down(acc, 16);
        acc += __shfl_down(acc, 8);
        acc += __shfl_down(acc, 4);
        acc += __shfl_down(acc, 2);
        acc += __shfl_down(acc, 1);
        if (lane == 0) part[wave] = tanh_fast(acc);
        __syncthreads();   // (C): all 16 rows in part[]

        // ---- wave0: pack + ONE coalesced 32B publish, then readout ----
        if (wave == 0) {
            if (lane < 8) {
                unsigned d = bf16_rne(part[2*lane]) | (bf16_rne(part[2*lane+1]) << 16);
                // drain old stores (clears ~compute-old, last readout), then
                // publish: visibility of publish implies clears visible.
                asm volatile("s_waitcnt vmcnt(0)" ::: "memory");
                agent_stu(p1 + 8 * b + lane, ~d);
            }
            // ---- readout of step s: fully off the critical path ----
            float rv = (lane < RPB) ? part[lane] : 0.0f;
            rv += __shfl_down(rv, 8);
            rv += __shfl_down(rv, 4);
            rv += __shfl_down(rv, 2);
            rv += __shfl_down(rv, 1);
            if (lane == 0 && b < (HALF / RPB)) {  // blocks 0..127 own rows<2048
                if (big) agent_st(parts + (size_t)s * 128 + b, rv);
                else     atomicAdd(accum + s, rv);
            }
            // fallback: adds for s-2 provably drained (publisher's step-(s-1)
            // pre-publish vmcnt covered its s-2 add; we observed h^s)
            if (!big && b == 0 && lane == 32 && s >= 2)
                out[s-2] = tanh_fast(agent_ld(accum + s - 2) * (1.0f / (float)HALF));
        }

        // rotate: p_i <- B[(s+1+i)&3]
        unsigned* tmp = p0; p0 = p1; p1 = p2; p2 = p3; p3 = tmp;
    }

    // ---- one-time device barrier so 'parts'/accum stores are visible ----
    asm volatile("s_waitcnt vmcnt(0)" ::: "memory");
    __syncthreads();
    if (t == 0) agent_stu(flags + b * 16, 1u);
    if (t < BLOCKS) {
        unsigned spins = 0;
        while (agent_ldu(flags + t * 16) == 0u) {
            __builtin_amdgcn_s_sleep(1);
            if (++spins > (1u << 22)) break;
        }
    }
    __syncthreads();

    if (big) {
        // all outputs in parallel: 128 block-partials per step
        for (int ss = b * 16 + wave; ss < n_steps; ss += BLOCKS * 16) {
            float v2 = agent_ld(parts + (size_t)ss * 128 + lane)
                     + agent_ld(parts + (size_t)ss * 128 + 64 + lane);
            v2 += __shfl_down(v2, 32);
            v2 += __shfl_down(v2, 16);
            v2 += __shfl_down(v2, 8);
            v2 += __shfl_down(v2, 4);
            v2 += __shfl_down(v2, 2);
            v2 += __shfl_down(v2, 1);
            if (lane == 0) out[ss] = tanh_fast(v2 * (1.0f / (float)HALF));
        }
    } else if (b == 0 && t == 0) {
        int k0 = (n_steps >= 2) ? n_steps - 2 : 0;
        for (int k = k0; k < n_steps; ++k)
            out[k] = tanh_fast(agent_ld(accum + k) * (1.0f / (float)HALF));
    }
}

extern "C" void kernel_launch(void* const* d_in, const int* in_sizes, int n_in,
                              void* d_out, int out_size, void* d_ws, size_t ws_size,
                              hipStream_t stream) {
    const float* W  = (const float*)d_in[0];
    const float* h0 = (const float*)d_in[1];
    const int*  pns = (const int*)d_in[2];
    float* out = (float*)d_out;
    float* ws  = (float*)d_ws;

    size_t need = ((size_t)WS_PART + (size_t)out_size * 128) * 4;
    int big = (ws_size >= need) ? 1 : 0;

    int n_init = out_size > N ? out_size : N;
    rnn_init<<<(n_init + 255) / 256, 256, 0, stream>>>(h0, ws, out_size);
    rnn_persistent<<<BLOCKS, TPB, 0, stream>>>(W, pns, out, ws, big);
}

// Round 10
// 10295.981 us; speedup vs baseline: 2.2828x; 1.1259x over previous
//
#include <hip/hip_runtime.h>

// TinyRNNPolicy: h_{t+1} = tanh(W h_t); action_t = tanh(mean(h_{t+1}[:2048]))
//
// R13 = R12 transport (proven 11.59ms) + LDS-pipe restructuring. R12's step
// (6790cy) carried ~3000cy of post-barrier LDS reads (16 waves x (8 W-b128
// + 8 h-b128)) while the LDS pipe idled during the ~1500cy detect window.
//  1) W HOISTED INTO THE WAIT: the 8 W b128s (this wave's step-constant
//     slice) are loaded into regs at loop top and pinned BEFORE the spin
//     (one asm, "memory" clobber). Detect latency now hides W's LDS time.
//     Decisive check: VGPR ~90+ (wd live across spin); ~52 = sunk.
//  2) COL-GROUP TILING kills h-read redundancy: waves = 4 row-groups x
//     4 col-groups (wave w: g=w>>2 rows 4g..4g+3, q=w&3 cols q*1024..+1023).
//     Each wave reads only its h quarter: 2 b128 vs 8 -> h LDS traffic
//     128KB -> 32KB/step. Reduce = 4 accs x (dpp_scan16 + 2 shfl); 4-way
//     col-partials combine via partc[64] in wave0's tail.
//  Layouts (conflict-free, lane-stride 16B):
//   wl[w*2048 + r*512 + x*256 + l*4 + e] = pack cols q*1024+x*512+8l+2e,+1
//   hd[x] = hs[q*512 + x*256 + l*4 + e]  (same col pairing; verified)
// Transport/protocol = R12 verbatim: packed-bf16 wire (~bits; dword==0
// only for double-NaN, tanh never makes it), ONE 8B atomic poll per
// thread, 32B coalesced wave0 publish, 4-buffer rotation with post-(A)
// clears, 2 barriers/step.

#define N 4096
#define HALF 2048
#define BLOCKS 256
#define TPB 1024
#define RPB 16
#define HWORDS (N / 2)        // 2048 packed dwords per h buffer

// ws layout (dword offsets); ws re-poisoned each launch -> init kernel.
#define WS_FLAGS 0            // 256 flags, stride 16 dwords (final barrier)
#define WS_HA    4096         // h buffer 0 (packed bf16 pairs, ~bits)
#define WS_HB    8192         // h buffer 1
#define WS_HC    12288        // h buffer 2
#define WS_HD    16384        // h buffer 3
#define WS_ACC   20480        // accum[out_size] (fallback path only)
#define WS_PART  24576        // parts[n_steps*128] (big path)

typedef unsigned u32x4 __attribute__((ext_vector_type(4)));

#if defined(__has_builtin)
#if __has_builtin(__builtin_amdgcn_fdot2_f32_bf16)
#define HAVE_DOT2 1
typedef __bf16 bf16x2 __attribute__((ext_vector_type(2)));
#endif
#endif
#ifndef HAVE_DOT2
#define HAVE_DOT2 0
#endif

__device__ __forceinline__ float agent_ld(const float* p) {
    return __hip_atomic_load(p, __ATOMIC_RELAXED, __HIP_MEMORY_SCOPE_AGENT);
}
__device__ __forceinline__ void agent_st(float* p, float v) {
    __hip_atomic_store(p, v, __ATOMIC_RELAXED, __HIP_MEMORY_SCOPE_AGENT);
}
__device__ __forceinline__ unsigned agent_ldu(const unsigned* p) {
    return __hip_atomic_load(p, __ATOMIC_RELAXED, __HIP_MEMORY_SCOPE_AGENT);
}
__device__ __forceinline__ void agent_stu(unsigned* p, unsigned v) {
    __hip_atomic_store(p, v, __ATOMIC_RELAXED, __HIP_MEMORY_SCOPE_AGENT);
}
__device__ __forceinline__ unsigned long long agent_ldu64(const unsigned long long* p) {
    return __hip_atomic_load(p, __ATOMIC_RELAXED, __HIP_MEMORY_SCOPE_AGENT);
}

__device__ __forceinline__ float tanh_fast(float x) {
    x = fminf(fmaxf(x, -15.0f), 15.0f);   // clamp avoids inf/inf
    float e = __expf(2.0f * x);
    return (e - 1.0f) / (e + 1.0f);       // exact 0 at x==0
}

__device__ __forceinline__ unsigned bf16_rne(float x) {   // fp32 -> bf16 (RNE)
    unsigned u = __float_as_uint(x);
    return (u + 0x7FFFu + ((u >> 16) & 1u)) >> 16;
}
__device__ __forceinline__ float bf_lo(unsigned d) { return __uint_as_float(d << 16); }
__device__ __forceinline__ float bf_hi(unsigned d) { return __uint_as_float(d & 0xFFFF0000u); }

// c += dot of 2 packed bf16 pairs (pairing-symmetric)
__device__ __forceinline__ float dot2bf(unsigned wp, unsigned hp, float c) {
#if HAVE_DOT2
    return __builtin_amdgcn_fdot2_f32_bf16(__builtin_bit_cast(bf16x2, wp),
                                           __builtin_bit_cast(bf16x2, hp),
                                           c, false);
#else
    c = fmaf(bf_lo(wp), bf_lo(hp), c);
    c = fmaf(bf_hi(wp), bf_hi(hp), c);
    return c;
#endif
}

// inclusive 16-lane prefix sum (DPP row_shr, VALU pipe); lane 15(+16k) = sum
__device__ __forceinline__ float dpp_scan16(float v) {
    int x;
    x = __builtin_amdgcn_update_dpp(0, __float_as_int(v), 0x111, 0xf, 0xf, true);
    v += __int_as_float(x);
    x = __builtin_amdgcn_update_dpp(0, __float_as_int(v), 0x112, 0xf, 0xf, true);
    v += __int_as_float(x);
    x = __builtin_amdgcn_update_dpp(0, __float_as_int(v), 0x114, 0xf, 0xf, true);
    v += __int_as_float(x);
    x = __builtin_amdgcn_update_dpp(0, __float_as_int(v), 0x118, 0xf, 0xf, true);
    v += __int_as_float(x);
    return v;
}

__global__ void rnn_init(const float* __restrict__ h0, float* __restrict__ ws, int n_out) {
    int i = blockIdx.x * blockDim.x + threadIdx.x;
    if (i < BLOCKS * 16) agent_stu((unsigned*)ws + WS_FLAGS + i, 0u);
    if (i < n_out) agent_st(ws + WS_ACC + i, 0.0f);
    if (i < HWORDS) {
        unsigned d = bf16_rne(h0[2*i]) | (bf16_rne(h0[2*i+1]) << 16);
        agent_stu((unsigned*)ws + WS_HA + i, ~d);   // h^0, packed ~bits
        agent_stu((unsigned*)ws + WS_HB + i, 0u);   // invalid
        agent_stu((unsigned*)ws + WS_HC + i, 0u);   // invalid
        agent_stu((unsigned*)ws + WS_HD + i, 0u);   // invalid
    }
}

__global__ void __launch_bounds__(TPB, 4)
rnn_persistent(const float* __restrict__ W, const int* __restrict__ pns,
               float* __restrict__ out, float* __restrict__ ws, int big) {
    const int b    = blockIdx.x;
    const int t    = threadIdx.x;
    const int lane = t & 63;
    const int wave = t >> 6;       // 0..15
    const int g    = wave >> 2;    // row group: rows 4g..4g+3
    const int q    = wave & 3;     // col group: cols q*1024..+1023

    __shared__ __align__(16) unsigned wl[32768];  // W bf16 pairs, tiled (128 KiB)
    __shared__ __align__(16) unsigned hs[HWORDS]; // h bf16 pairs (8 KiB)
    __shared__ __align__(16) float partc[64];     // partc[w*4+r]: col-partials

    // ---- one-time: W tile (4 rows x 1024 cols) -> LDS packed bf16 ----
    // wl[wave*2048 + r*512 + x*256 + lane*4 + e] = pack(W[row][c], W[row][c+1]),
    // c = q*1024 + x*512 + lane*8 + 2e  -> consecutive-lane b128 on read.
    {
#pragma unroll
        for (int r = 0; r < 4; ++r) {
            const float* Wr = W + (size_t)(b * RPB + 4 * g + r) * N + q * 1024;
#pragma unroll
            for (int x = 0; x < 2; ++x) {
                const float* c0 = Wr + x * 512 + lane * 8;
                float4 va = *(const float4*)(c0);
                float4 vb = *(const float4*)(c0 + 4);
                u32x4 d;
                d.x = bf16_rne(va.x) | (bf16_rne(va.y) << 16);
                d.y = bf16_rne(va.z) | (bf16_rne(va.w) << 16);
                d.z = bf16_rne(vb.x) | (bf16_rne(vb.y) << 16);
                d.w = bf16_rne(vb.z) | (bf16_rne(vb.w) << 16);
                *(u32x4*)&wl[wave * 2048 + r * 512 + x * 256 + lane * 4] = d;
            }
        }
    }
    __syncthreads();

    const int n_steps = *pns;

    unsigned* flags = (unsigned*)ws + WS_FLAGS;
    float* accum = ws + WS_ACC;
    float* parts = ws + WS_PART;

    // rotation: read p0=B[s&3], write p1=B[(s+1)&3], clear p2=B[(s+2)&3]
    unsigned* p0 = (unsigned*)ws + WS_HA;
    unsigned* p1 = (unsigned*)ws + WS_HB;
    unsigned* p2 = (unsigned*)ws + WS_HC;
    unsigned* p3 = (unsigned*)ws + WS_HD;

    const unsigned* wbase = wl + wave * 2048 + lane * 4;
    const unsigned* hbase = hs + q * 512 + lane * 4;

    for (int s = 0; s < n_steps; ++s) {
        // ---- hoist W slice into regs BEFORE the spin (pin w/ mem clobber:
        //      the spin can't float above it, the loads can't sink below) ----
        u32x4 w00 = *(const u32x4*)(wbase +    0), w01 = *(const u32x4*)(wbase + 256);
        u32x4 w10 = *(const u32x4*)(wbase +  512), w11 = *(const u32x4*)(wbase + 768);
        u32x4 w20 = *(const u32x4*)(wbase + 1024), w21 = *(const u32x4*)(wbase + 1280);
        u32x4 w30 = *(const u32x4*)(wbase + 1536), w31 = *(const u32x4*)(wbase + 1792);
        asm volatile("" : "+v"(w00), "+v"(w01), "+v"(w10), "+v"(w11),
                          "+v"(w20), "+v"(w21), "+v"(w30), "+v"(w31) :: "memory");

        // ---- fused spin + ingest: ONE 8B load, both dwords valid ----
        unsigned lo, hi;
        {
            const unsigned long long* src = (const unsigned long long*)(p0 + 2 * t);
            unsigned spins = 0;
            for (;;) {
                unsigned long long qv = agent_ldu64(src);
                lo = (unsigned)qv; hi = (unsigned)(qv >> 32);
                if (min(lo, hi) != 0u) break;
                __builtin_amdgcn_s_sleep(1);
                if (++spins > (1u << 22)) break;   // fail loud, don't hang
            }
        }
        // stage: raw packed copy (no repack -- dot2 eats pairs directly)
        *(uint2*)&hs[2 * t] = make_uint2(~lo, ~hi);
        __syncthreads();   // (A): all of h^s observed + staged block-wide

        // clear buffer last read at s-2 (race-free post-(A); ordered before
        // its rewrite at s+1 by wave0's pre-publish vmcnt(0))
        if (t < 8) agent_stu(p2 + 8 * b + t, 0u);

        // ---- h quarter: 2 conflict-free b128; 32 dot2 over 4 rows ----
        u32x4 h0v = *(const u32x4*)(hbase + 0);
        u32x4 h1v = *(const u32x4*)(hbase + 256);
        float a0 = 0.f, a1 = 0.f, a2 = 0.f, a3 = 0.f;
#pragma unroll
        for (int e = 0; e < 4; ++e) {
            a0 = dot2bf(w00[e], h0v[e], a0); a0 = dot2bf(w01[e], h1v[e], a0);
            a1 = dot2bf(w10[e], h0v[e], a1); a1 = dot2bf(w11[e], h1v[e], a1);
            a2 = dot2bf(w20[e], h0v[e], a2); a2 = dot2bf(w21[e], h1v[e], a2);
            a3 = dot2bf(w30[e], h0v[e], a3); a3 = dot2bf(w31[e], h1v[e], a3);
        }
        // ---- 64-lane reduce: dpp scan16 (VALU) + 2 shfl per acc ----
        a0 = dpp_scan16(a0); a1 = dpp_scan16(a1);
        a2 = dpp_scan16(a2); a3 = dpp_scan16(a3);
        a0 += __shfl_down(a0, 16); a1 += __shfl_down(a1, 16);
        a2 += __shfl_down(a2, 16); a3 += __shfl_down(a3, 16);
        a0 += __shfl_down(a0, 32); a1 += __shfl_down(a1, 32);
        a2 += __shfl_down(a2, 32); a3 += __shfl_down(a3, 32);
        if (lane == 15) {
            *(float4*)&partc[wave * 4] = make_float4(a0, a1, a2, a3);
        }
        __syncthreads();   // (C): all 64 col-partials in partc[]

        // ---- wave0: combine 4 col-groups, tanh, pack, publish, readout ----
        if (wave == 0) {
            float hv = 0.0f;
            if (lane < 16) {
                int gg = lane >> 2, rr = lane & 3;
                float s0 = partc[(gg * 4 + 0) * 4 + rr];
                float s1 = partc[(gg * 4 + 1) * 4 + rr];
                float s2 = partc[(gg * 4 + 2) * 4 + rr];
                float s3 = partc[(gg * 4 + 3) * 4 + rr];
                hv = tanh_fast((s0 + s1) + (s2 + s3));
            }
            float e0 = __shfl(hv, 2 * lane);       // rows 2l, 2l+1 (lane<8)
            float e1 = __shfl(hv, 2 * lane + 1);
            // drain old stores (clears, prior readout), then publish 32B.
            asm volatile("s_waitcnt vmcnt(0)" ::: "memory");
            if (lane < 8) {
                unsigned d = bf16_rne(e0) | (bf16_rne(e1) << 16);
                agent_stu(p1 + 8 * b + lane, ~d);
            }
            // ---- readout of step s: fully off the critical path ----
            float rv = (lane < 16) ? hv : 0.0f;
            rv += __shfl_down(rv, 8);
            rv += __shfl_down(rv, 4);
            rv += __shfl_down(rv, 2);
            rv += __shfl_down(rv, 1);
            if (lane == 0 && b < (HALF / RPB)) {  // blocks 0..127 own rows<2048
                if (big) agent_st(parts + (size_t)s * 128 + b, rv);
                else     atomicAdd(accum + s, rv);
            }
            // fallback: adds for s-2 provably drained (publisher's step-(s-1)
            // pre-publish vmcnt covered its s-2 add; we observed h^s)
            if (!big && b == 0 && lane == 32 && s >= 2)
                out[s-2] = tanh_fast(agent_ld(accum + s - 2) * (1.0f / (float)HALF));
        }

        // rotate: p_i <- B[(s+1+i)&3]
        unsigned* tmp = p0; p0 = p1; p1 = p2; p2 = p3; p3 = tmp;
    }

    // ---- one-time device barrier so 'parts'/accum stores are visible ----
    asm volatile("s_waitcnt vmcnt(0)" ::: "memory");
    __syncthreads();
    if (t == 0) agent_stu(flags + b * 16, 1u);
    if (t < BLOCKS) {
        unsigned spins = 0;
        while (agent_ldu(flags + t * 16) == 0u) {
            __builtin_amdgcn_s_sleep(1);
            if (++spins > (1u << 22)) break;
        }
    }
    __syncthreads();

    if (big) {
        // all outputs in parallel: 128 block-partials per step
        for (int ss = b * 16 + wave; ss < n_steps; ss += BLOCKS * 16) {
            float v2 = agent_ld(parts + (size_t)ss * 128 + lane)
                     + agent_ld(parts + (size_t)ss * 128 + 64 + lane);
            v2 += __shfl_down(v2, 32);
            v2 += __shfl_down(v2, 16);
            v2 += __shfl_down(v2, 8);
            v2 += __shfl_down(v2, 4);
            v2 += __shfl_down(v2, 2);
            v2 += __shfl_down(v2, 1);
            if (lane == 0) out[ss] = tanh_fast(v2 * (1.0f / (float)HALF));
        }
    } else if (b == 0 && t == 0) {
        int k0 = (n_steps >= 2) ? n_steps - 2 : 0;
        for (int k = k0; k < n_steps; ++k)
            out[k] = tanh_fast(agent_ld(accum + k) * (1.0f / (float)HALF));
    }
}

extern "C" void kernel_launch(void* const* d_in, const int* in_sizes, int n_in,
                              void* d_out, int out_size, void* d_ws, size_t ws_size,
                              hipStream_t stream) {
    const float* W  = (const float*)d_in[0];
    const float* h0 = (const float*)d_in[1];
    const int*  pns = (const int*)d_in[2];
    float* out = (float*)d_out;
    float* ws  = (float*)d_ws;

    size_t need = ((size_t)WS_PART + (size_t)out_size * 128) * 4;
    int big = (ws_size >= need) ? 1 : 0;

    int n_init = out_size > N ? out_size : N;
    rnn_init<<<(n_init + 255) / 256, 256, 0, stream>>>(h0, ws, out_size);
    rnn_persistent<<<BLOCKS, TPB, 0, stream>>>(W, pns, out, ws, big);
}